// Round 1
// baseline (384.824 us; speedup 1.0000x reference)
//
#include <hip/hip_runtime.h>
#include <hip/hip_bf16.h>
#include <math.h>

using u16 = unsigned short;
using u32 = unsigned int;

typedef __attribute__((ext_vector_type(8))) short s16x8;
typedef __attribute__((ext_vector_type(4))) float f32x4;

#define B_  4
#define L_  8192
#define D_  512
#define H_  8
#define G_  4

// ---------- helpers ----------
__device__ __forceinline__ float bf2f(u16 u) {
    u32 x = ((u32)u) << 16;
    return __uint_as_float(x);
}
__device__ __forceinline__ u16 f2bf(float f) {  // round-to-nearest-even
    u32 x = __float_as_uint(f);
    u32 lsb = (x >> 16) & 1u;
    x += 0x7FFFu + lsb;
    return (u16)(x >> 16);
}
__device__ __forceinline__ void async16(const void* g, void* l) {
    __builtin_amdgcn_global_load_lds((const __attribute__((address_space(1))) u32*)g,
                                     (__attribute__((address_space(3))) u32*)l, 16, 0, 0);
}
// s_waitcnt immediates (gfx9): vmcnt low4 bits[3:0], high2 bits[15:14]; exp [6:4]; lgkm [11:8]
#define WAIT_VM16  0x4F70
#define WAIT_VM8   0x0F78
#define WAIT_VM0   0x0F70
#define WAIT_LGKM0 0xC07F

// ---------- fused prep: cast x -> bf16 | pack weights | compose offset convs ----------
// blocks [0,16384): cast; [16384,16768): pack (128 per weight); [16768,16771): weff
#define CAST_BLOCKS 16384
#define PACK_BLOCKS 384
__global__ __launch_bounds__(256) void prep_kernel(const float* __restrict__ x,
                                                   u16* __restrict__ x_bf,
                                                   const float* __restrict__ Wq,
                                                   const float* __restrict__ Wk,
                                                   const float* __restrict__ Wv,
                                                   u16* __restrict__ Pq,
                                                   u16* __restrict__ Pk,
                                                   u16* __restrict__ Pv,
                                                   const float* __restrict__ W1,
                                                   const float* __restrict__ b1,
                                                   const float* __restrict__ W2,
                                                   const float* __restrict__ b2,
                                                   float* __restrict__ weff) {
    const int bid = blockIdx.x;
    const int tid = threadIdx.x;
    if (bid < CAST_BLOCKS) {
        // cast fp32 -> bf16, 4 floats/thread
        const int i = bid * 256 + tid;            // < 4194304 exactly
        float4 v = ((const float4*)x)[i];
        ushort4 o;
        o.x = f2bf(v.x); o.y = f2bf(v.y); o.z = f2bf(v.z); o.w = f2bf(v.w);
        ((ushort4*)x_bf)[i] = o;
    } else if (bid < CAST_BLOCKS + PACK_BLOCKS) {
        // pack a 512x512 f32 weight into MFMA B-fragment order (bf16)
        const int pb = bid - CAST_BLOCKS;
        const int wsel = pb >> 7;                  // 0..2
        const int xb = pb & 127;
        const int g = xb * 4 + (tid >> 6);         // 0..511 = cb*16+kc
        const int lane = tid & 63;
        const int cb = g >> 4, kc = g & 15;
        const int q = lane >> 4, fm = lane & 15;
        const float* W = (wsel == 0) ? Wq : (wsel == 1) ? Wk : Wv;
        u16* P = (wsel == 0) ? Pq : (wsel == 1) ? Pk : Pv;
        const float* src = W + (size_t)(cb * 16 + fm) * 512 + kc * 32 + q * 8;
        float4 a = *(const float4*)src;
        float4 b = *(const float4*)(src + 4);
        ushort4 o0, o1;
        o0.x = f2bf(a.x); o0.y = f2bf(a.y); o0.z = f2bf(a.z); o0.w = f2bf(a.w);
        o1.x = f2bf(b.x); o1.y = f2bf(b.y); o1.z = f2bf(b.z); o1.w = f2bf(b.w);
        u16* dst = P + (size_t)g * 512 + lane * 8;
        *(ushort4*)dst = o0;
        *(ushort4*)(dst + 4) = o1;
    } else {
        // compose conv1(128x128x5) + conv2(1x128x1) -> weff (642 floats)
        const int idx = (bid - CAST_BLOCKS - PACK_BLOCKS) * 256 + tid;  // [0,768)
        if (idx < 640) {
            int cin = idx / 5, dk = idx % 5;
            float acc = 0.f;
            for (int c = 0; c < 128; ++c) acc += W2[c] * W1[(c * 128 + cin) * 5 + dk];
            weff[idx] = acc;
        } else if (idx == 640) {
            float s = b2[0];
            for (int c = 0; c < 128; ++c) s += W2[c] * b1[c];
            weff[640] = s;              // composed bias (t>=2)
        } else if (idx == 641) {
            weff[641] = b2[0];          // conv2-pad-only bias (t<2)
        }
    }
}

// ---------- fused offset conv + tanh + grid_sample position precompute ----------
__global__ __launch_bounds__(256) void offsets_kernel(const u16* __restrict__ qT,
                                                      const float* __restrict__ weff,
                                                      int* __restrict__ p0o,
                                                      float* __restrict__ w1o) {
    __shared__ u16 qs[128 * 72];   // 128 ch x 72 l (l from t0-8), 18.4 KB
    __shared__ float wf[642];
    __shared__ float red[4][64];
    const int tid = threadIdx.x;
    const int t0 = blockIdx.x * 64;
    const int bg = blockIdx.y;
    const int b = bg >> 2, g = bg & 3;
    for (int i = tid; i < 642; i += 256) wf[i] = weff[i];
    for (int i = tid; i < 128 * 9; i += 256) {
        const int ch = i / 9, seg = i - ch * 9;
        const int l = t0 - 8 + seg * 8;
        s16x8 val = {0, 0, 0, 0, 0, 0, 0, 0};
        if (l >= 0)
            val = *(const s16x8*)(qT + (size_t)(b * D_ + g * 128 + ch) * L_ + l);
        *(s16x8*)(qs + ch * 72 + seg * 8) = val;
    }
    __syncthreads();
    const int w = tid >> 6, lane = tid & 63;
    float acc = 0.f;
    for (int c = 0; c < 32; ++c) {
        const int ch = w * 32 + c;
        const u16* row = qs + ch * 72 + lane + 4;   // lc = (t-t0)+4+dk
        const float* wr = wf + ch * 5;
        #pragma unroll
        for (int dk = 0; dk < 5; ++dk) acc += wr[dk] * bf2f(row[dk]);
    }
    red[w][lane] = acc;
    __syncthreads();
    if (w == 0) {
        const float s = red[0][lane] + red[1][lane] + red[2][lane] + red[3][lane];
        const int t = t0 + lane;
        const float o2 = (t >= 2) ? (s + wf[640]) : wf[641];
        const double offv = tanh((double)o2) * 5.0;
        const double vg  = (double)t + offv;
        const double gg  = 2.0 * vg / 8195.0 - 1.0;          // n-1 = L+3 = 8195
        const double pos = ((gg + 1.0) * 8192.0 - 1.0) * 0.5;
        const double p0d = floor(pos);
        p0o[(size_t)bg * L_ + t] = (int)p0d;
        w1o[(size_t)bg * L_ + t] = (float)(pos - p0d);
    }
}

// ---------- bilinear gather from bf16 x: 8 d-channels per thread (16B loads) ----------
__global__ __launch_bounds__(256) void sample_bf16(const u16* __restrict__ xb,
                                                   const int* __restrict__ p0i,
                                                   const float* __restrict__ w1f,
                                                   u16* __restrict__ xs) {
    const size_t idx = (size_t)blockIdx.x * 256 + threadIdx.x;   // B*L*64
    const int d8 = (int)(idx & 63);             // 8-channel group
    const int t = (int)((idx >> 6) & 8191);
    const int b = (int)(idx >> 19);
    const int g = d8 >> 4;
    const size_t og = (size_t)(b * 4 + g) * L_ + t;
    const int p0 = p0i[og];
    const float w1 = w1f[og];
    const float w0 = 1.f - w1;
    const int p1 = p0 + 1;
    s16x8 a = {0, 0, 0, 0, 0, 0, 0, 0}, c = {0, 0, 0, 0, 0, 0, 0, 0};
    if (p0 >= 0 && p0 < L_) a = *(const s16x8*)(xb + ((size_t)b * L_ + p0) * D_ + d8 * 8);
    if (p1 >= 0 && p1 < L_) c = *(const s16x8*)(xb + ((size_t)b * L_ + p1) * D_ + d8 * 8);
    u16 o[8];
    #pragma unroll
    for (int j = 0; j < 8; ++j)
        o[j] = f2bf(bf2f(((const u16*)&a)[j]) * w0 + bf2f(((const u16*)&c)[j]) * w1);
    *(s16x8*)(xs + idx * 8) = *(const s16x8*)o;
}

// ---------- fallback: bilinear gather from fp32 x, 4 d-channels per thread ----------
__global__ __launch_bounds__(256) void sample_f32(const float* __restrict__ x,
                                                  const int* __restrict__ p0i,
                                                  const float* __restrict__ w1f,
                                                  u16* __restrict__ xs) {
    const size_t idx4 = (size_t)blockIdx.x * 256 + threadIdx.x;   // B*L*D/4
    const int d4 = (int)(idx4 & 127);           // 4-channel group
    const int t = (int)((idx4 >> 7) & 8191);
    const int b = (int)(idx4 >> 20);
    const int g = d4 >> 5;
    const size_t og = (size_t)(b * 4 + g) * L_ + t;
    const int p0 = p0i[og];
    const float w1 = w1f[og];
    const float w0 = 1.f - w1;
    const int p1 = p0 + 1;
    float4 v0 = {0.f, 0.f, 0.f, 0.f}, v1 = {0.f, 0.f, 0.f, 0.f};
    if (p0 >= 0 && p0 < L_) v0 = *(const float4*)(x + ((size_t)b * L_ + p0) * D_ + d4 * 4);
    if (p1 >= 0 && p1 < L_) v1 = *(const float4*)(x + ((size_t)b * L_ + p1) * D_ + d4 * 4);
    ushort4 o;
    o.x = f2bf(v0.x * w0 + v1.x * w1);
    o.y = f2bf(v0.y * w0 + v1.y * w1);
    o.z = f2bf(v0.z * w0 + v1.z * w1);
    o.w = f2bf(v0.w * w0 + v1.w * w1);
    ((ushort4*)xs)[idx4] = o;
}

// ---------- MFMA GEMM, A wave-private LDS (3-deep), B direct from packed weights ----
// MODE 0: q    -> transposed bf16 out (qT)
// MODE 1: k|v  -> sel=0: transposed bf16 (kT); sel=1: row-major bf16 + rel (v). grid 2x.
// MODE 2: final-> row-major fp32 out, P indexed per-batch
template <int MODE>
__global__ __launch_bounds__(256) void gemm_kernel(const u16* __restrict__ A,
                                                   const u16* __restrict__ P0,
                                                   const u16* __restrict__ P1,
                                                   const float* __restrict__ bias0,
                                                   const float* __restrict__ bias1,
                                                   const float* __restrict__ rel,
                                                   void* __restrict__ out0,
                                                   void* __restrict__ out1) {
    __shared__ short lds[4][3][2048];   // per-wave A triple-buffer = 48 KB
    const int tid = threadIdx.x;
    const int wave = tid >> 6, lane = tid & 63;
    const int bid = blockIdx.x;
    const int xcd = bid & 7;
    const int kk_ = bid >> 3;
    int r0, c0, sel;
    if (MODE == 1) { r0 = (xcd * 32 + (kk_ >> 3)) * 128; sel = (kk_ >> 2) & 1; c0 = (kk_ & 3) * 128; }
    else           { r0 = (xcd * 32 + (kk_ >> 2)) * 128; sel = 0;              c0 = (kk_ & 3) * 128; }
    const u16* P = (MODE == 1 && sel) ? P1 : P0;
    if (MODE == 2) P += (size_t)(r0 >> 13) * 262144;       // per-batch packed M
    const float* bias = (MODE == 1 && sel) ? bias1 : bias0;
    void* out = (MODE == 1 && sel) ? out1 : out0;

    const int wm = (wave >> 1) * 64, wn = (wave & 1) * 64;
    const int srow = lane >> 2;
    const int scol = ((lane & 3) ^ ((srow >> 1) & 3)) * 8;   // XOR-swizzled 16B block
    const u16* gA = A + (size_t)(r0 + wm) * D_ + scol;
    short* bufA[3] = { &lds[wave][0][0], &lds[wave][1][0], &lds[wave][2][0] };
    const int cbase = (c0 + wn) >> 4;

    f32x4 acc[4][4];
    #pragma unroll
    for (int mi = 0; mi < 4; ++mi)
        #pragma unroll
        for (int ni = 0; ni < 4; ++ni) acc[mi][ni] = (f32x4){0.f, 0.f, 0.f, 0.f};

    const int fm = lane & 15;
    const int sblk = ((lane >> 4) ^ ((fm >> 1) & 3)) * 8;    // inverse swizzle

    s16x8 bfrag[3][4];

    auto issueA = [&](int slot, int it) {
        const int k0 = it * 32;
        #pragma unroll
        for (int j = 0; j < 4; ++j)
            async16(gA + (size_t)(j * 16 + srow) * D_ + k0, bufA[slot] + j * 512);
    };
    auto issueB = [&](int slot, int it) {
        #pragma unroll
        for (int ni = 0; ni < 4; ++ni)
            bfrag[slot][ni] = *(const s16x8*)(P + ((size_t)((cbase + ni) * 16 + it) * 64 + lane) * 8);
    };

    issueA(0, 0); issueB(0, 0);
    issueA(1, 1); issueB(1, 1);
    issueA(2, 2); issueB(2, 2);

    #pragma unroll
    for (int it = 0; it < 16; ++it) {
        const int slot = it % 3;
        if (it < 14)       __builtin_amdgcn_s_waitcnt(WAIT_VM16);
        else if (it == 14) __builtin_amdgcn_s_waitcnt(WAIT_VM8);
        else               __builtin_amdgcn_s_waitcnt(WAIT_VM0);
        __builtin_amdgcn_sched_barrier(0);
        s16x8 af[4];
        #pragma unroll
        for (int mi = 0; mi < 4; ++mi)
            af[mi] = *(const s16x8*)(bufA[slot] + mi * 512 + fm * 32 + sblk);
        __builtin_amdgcn_s_waitcnt(WAIT_LGKM0);              // A frags in regs
        __builtin_amdgcn_sched_barrier(0);                   // pin before DMA reissue
        if (it < 13) issueA(slot, it + 3);
        #pragma unroll
        for (int mi = 0; mi < 4; ++mi)
            #pragma unroll
            for (int ni = 0; ni < 4; ++ni)
                acc[mi][ni] = __builtin_amdgcn_mfma_f32_16x16x32_bf16(af[mi], bfrag[slot][ni], acc[mi][ni], 0, 0, 0);
        if (it < 13) issueB(slot, it + 3);
    }

    // epilogue: D layout col = lane&15, row = (lane>>4)*4 + reg
    const int fn = lane & 15;
    const int q4 = (lane >> 4) * 4;
    const bool transposed = (MODE == 0) || (MODE == 1 && sel == 0);
    #pragma unroll
    for (int mi = 0; mi < 4; ++mi) {
        #pragma unroll
        for (int ni = 0; ni < 4; ++ni) {
            const int c = c0 + wn + ni * 16 + fn;
            const float bsum = bias[c];
            if (MODE == 2) {
                #pragma unroll
                for (int rg = 0; rg < 4; ++rg) {
                    const int r = r0 + wm + mi * 16 + q4 + rg;
                    ((float*)out)[(size_t)r * D_ + c] = acc[mi][ni][rg] + bsum;
                }
            } else if (transposed) {
                const int r_ = r0 + wm + mi * 16 + q4;   // 4 consecutive rows
                const int bb = r_ >> 13;
                const int l  = r_ & (L_ - 1);
                ushort4 o;
                o.x = f2bf(acc[mi][ni][0] + bsum);
                o.y = f2bf(acc[mi][ni][1] + bsum);
                o.z = f2bf(acc[mi][ni][2] + bsum);
                o.w = f2bf(acc[mi][ni][3] + bsum);
                *(ushort4*)((u16*)out + (size_t)(bb * D_ + c) * L_ + l) = o;
            } else {
                const int r_ = r0 + wm + mi * 16 + q4;
                const int l  = r_ & (L_ - 1);
                const float4 rl = *(const float4*)(rel + (size_t)c * L_ + l);
                ((u16*)out)[(size_t)(r_ + 0) * D_ + c] = f2bf(acc[mi][ni][0] + bsum + rl.x);
                ((u16*)out)[(size_t)(r_ + 1) * D_ + c] = f2bf(acc[mi][ni][1] + bsum + rl.y);
                ((u16*)out)[(size_t)(r_ + 2) * D_ + c] = f2bf(acc[mi][ni][2] + bsum + rl.z);
                ((u16*)out)[(size_t)(r_ + 3) * D_ + c] = f2bf(acc[mi][ni][3] + bsum + rl.w);
            }
        }
    }
}

// ---------- channel-attention scores via MFMA, split-K partials ----------
__global__ __launch_bounds__(256) void scores_partial(const u16* __restrict__ qT,
                                                      const u16* __restrict__ kT,
                                                      float* __restrict__ part) {
    __shared__ u16 qs[64 * 136];
    __shared__ u16 ks[64 * 136];
    const int chunk = blockIdx.x;   // 0..15, 512 l each
    const int bh = blockIdx.y;      // 0..31
    const int b = bh >> 3, h = bh & 7;
    const int tid = threadIdx.x;
    const int wave = tid >> 6, lane = tid & 63;
    const int wr = (wave >> 1) * 32;
    const int wc = (wave & 1) * 32;
    f32x4 acc[2][2];
    #pragma unroll
    for (int mi = 0; mi < 2; ++mi)
        #pragma unroll
        for (int ni = 0; ni < 2; ++ni) acc[mi][ni] = (f32x4){0.f, 0.f, 0.f, 0.f};
    const size_t base = (size_t)(b * D_ + h * 64) * L_;
    const int m = lane & 15, q = lane >> 4;
    for (int iter = 0; iter < 4; ++iter) {
        const int l0 = chunk * 512 + iter * 128;
        __syncthreads();
        for (int i = tid; i < 1024; i += 256) {
            const int lb = i & 15, ch = i >> 4;
            const size_t gidx = base + (size_t)ch * L_ + l0 + lb * 8;
            *(s16x8*)(qs + ch * 136 + lb * 8) = *(const s16x8*)(qT + gidx);
            *(s16x8*)(ks + ch * 136 + lb * 8) = *(const s16x8*)(kT + gidx);
        }
        __syncthreads();
        #pragma unroll
        for (int kst = 0; kst < 4; ++kst) {
            const int kk = kst * 32 + q * 8;
            s16x8 af[2], bfr[2];
            af[0]  = *(const s16x8*)(qs + (wr + m) * 136 + kk);
            af[1]  = *(const s16x8*)(qs + (wr + 16 + m) * 136 + kk);
            bfr[0] = *(const s16x8*)(ks + (wc + m) * 136 + kk);
            bfr[1] = *(const s16x8*)(ks + (wc + 16 + m) * 136 + kk);
            #pragma unroll
            for (int mi = 0; mi < 2; ++mi)
                #pragma unroll
                for (int ni = 0; ni < 2; ++ni)
                    acc[mi][ni] = __builtin_amdgcn_mfma_f32_16x16x32_bf16(af[mi], bfr[ni], acc[mi][ni], 0, 0, 0);
        }
    }
    float* dst = part + (size_t)(bh * 16 + chunk) * 4096;
    const int q4 = (lane >> 4) * 4;
    #pragma unroll
    for (int mi = 0; mi < 2; ++mi) {
        #pragma unroll
        for (int ni = 0; ni < 2; ++ni) {
            const int j = wc + ni * 16 + m;
            #pragma unroll
            for (int rg = 0; rg < 4; ++rg) {
                const int i = wr + mi * 16 + q4 + rg;
                dst[i * 64 + j] = acc[mi][ni][rg];
            }
        }
    }
}

// ---------- sum partials, scale, softmax over last dim ----------
__global__ __launch_bounds__(256) void softmax_kernel(const float* __restrict__ part,
                                                      float* __restrict__ attn) {
    const int tid = threadIdx.x;
    const int wave = tid >> 6, lane = tid & 63;
    const int row = blockIdx.x * 4 + wave;
    const int bh = row >> 6, i = row & 63;
    float s = 0.f;
    #pragma unroll
    for (int c = 0; c < 16; ++c) s += part[((size_t)(bh * 16 + c)) * 4096 + i * 64 + lane];
    s *= 0.04419417382415922f;               // 512^-0.5
    float m = s;
    for (int off = 32; off > 0; off >>= 1) m = fmaxf(m, __shfl_xor(m, off));
    float e = expf(s - m);
    float sum = e;
    for (int off = 32; off > 0; off >>= 1) sum += __shfl_xor(sum, off);
    attn[(size_t)bh * 4096 + i * 64 + lane] = e / sum;
}

// ---------- M[b] = Wout * blockdiag(attn[b]) written in packed B-fragment order ----
__global__ __launch_bounds__(256) void build_M(const float* __restrict__ Wout,
                                               const float* __restrict__ attn,
                                               u16* __restrict__ Mpack) {
    const int idx = blockIdx.x * 256 + threadIdx.x;   // b*512*512 + o*512 + col
    const int col = idx & 511;                        // k (v-channel)
    const int o = (idx >> 9) & 511;                   // out-channel (GEMM col c)
    const int b = idx >> 18;
    const int h = col >> 6, j0 = col & 63;
    const float* wr = Wout + o * 512 + h * 64;
    const float* ar = attn + (size_t)(b * H_ + h) * 4096 + j0;
    float s = 0.f;
    #pragma unroll 8
    for (int i = 0; i < 64; ++i) s += wr[i] * ar[i * 64];
    const int cb = o >> 4, fm = o & 15;
    const int kc = col >> 5, q = (col >> 3) & 3, j = col & 7;
    Mpack[(size_t)b * 262144 + ((size_t)(cb * 16 + kc) * 64 + q * 16 + fm) * 8 + j] = f2bf(s);
}

extern "C" void kernel_launch(void* const* d_in, const int* in_sizes, int n_in,
                              void* d_out, int out_size, void* d_ws, size_t ws_size,
                              hipStream_t stream) {
    const float* x    = (const float*)d_in[0];
    const float* Wq   = (const float*)d_in[1];
    const float* bq   = (const float*)d_in[2];
    const float* Wk   = (const float*)d_in[3];
    const float* bk   = (const float*)d_in[4];
    const float* Wv   = (const float*)d_in[5];
    const float* bv   = (const float*)d_in[6];
    const float* Wo1  = (const float*)d_in[7];
    const float* bo1  = (const float*)d_in[8];
    const float* Wo2  = (const float*)d_in[9];
    const float* bo2  = (const float*)d_in[10];
    const float* rel  = (const float*)d_in[11];
    const float* Wout = (const float*)d_in[12];
    const float* bout = (const float*)d_in[13];

    char* ws = (char*)d_ws;
    const size_t MB = 1024ull * 1024ull;
    const bool big = ws_size >= 165ull * MB;   // bf16-sample path needs ~163.2 MB

    u16* x_bf = (u16*)(ws);                    // 32 MB
    u16* qT   = (u16*)(ws + 32 * MB);          // 32 MB, [b*D+ch][l]
    u16* kT   = (u16*)(ws + 64 * MB);          // 32 MB, [b*D+ch][l]
    u16* v_bf = (u16*)(ws + 96 * MB);          // 32 MB, row-major

    u16*   xs;     // sampled x (bf16 row-major), A-input of gemm_kv
    u16*   Pq; u16* Pk; u16* Pv;
    float* weff; int* p0i; float* w1f;
    float* part; float* attn; u16* Mpack;

    if (big) {
        // xs lives at 128..160 MB while needed (disp 5-6); part/attn/Mpack
        // reuse the same window afterwards (written only at disp 7+, xs dead).
        xs    = (u16*)(ws + 128 * MB);                         // 32 MB
        part  = (float*)(ws + 128 * MB);                       // 8 MB (after xs dead)
        attn  = (float*)((char*)part + 8 * MB);                // 512 KB
        Mpack = (u16*)((char*)attn + 524288);                  // 2 MB
        Pq    = (u16*)(ws + 160 * MB);                         // 512 KB each
        Pk    = Pq + 262144;
        Pv    = Pk + 262144;
        weff  = (float*)(ws + 162 * MB);                       // 642 floats
        p0i   = (int*)(ws + 162 * MB + 65536);                 // 512 KB
        w1f   = (float*)((char*)p0i + 524288);                 // 512 KB
    } else {
        // legacy layout: xs overwrites x_bf (fp32 sampling; x_bf dead after gemm_q)
        xs    = x_bf;
        Pq    = (u16*)(ws + 128 * MB);
        Pk    = Pq + 262144;
        Pv    = Pk + 262144;
        weff  = (float*)(ws + 130 * MB);
        p0i   = (int*)(ws + 130 * MB + 65536);
        w1f   = (float*)((char*)p0i + 524288);
        part  = (float*)((char*)w1f + 524288);
        attn  = (float*)((char*)part + 8 * MB);
        Mpack = (u16*)((char*)attn + 524288);
    }

    // 1. fused prep: cast x -> bf16, pack Wq/Wk/Wv, compose offset convs
    prep_kernel<<<CAST_BLOCKS + PACK_BLOCKS + 3, 256, 0, stream>>>(
        x, x_bf, Wq, Wk, Wv, Pq, Pk, Pv, Wo1, bo1, Wo2, bo2, weff);
    // 2. q = x @ Wq^T  (stored transposed)
    gemm_kernel<0><<<1024, 256, 0, stream>>>(x_bf, Pq, nullptr, bq, nullptr, nullptr, (void*)qT, nullptr);
    // 3. offsets -> sampling positions (reads qT)
    offsets_kernel<<<dim3(128, 16), 256, 0, stream>>>(qT, weff, p0i, w1f);
    // 4. bilinear sample
    if (big) sample_bf16<<<8192, 256, 0, stream>>>(x_bf, p0i, w1f, xs);
    else     sample_f32<<<16384, 256, 0, stream>>>(x, p0i, w1f, xs);
    // 5. k (transposed) + v (row-major + rel) in ONE dispatch
    gemm_kernel<1><<<2048, 256, 0, stream>>>(xs, Pk, Pv, bk, bv, rel, (void*)kT, (void*)v_bf);
    // 6. scores (MFMA) + softmax
    scores_partial<<<dim3(16, 32), 256, 0, stream>>>(qT, kT, part);
    softmax_kernel<<<512, 256, 0, stream>>>(part, attn);
    // 7. fold attn into output projection (packed layout)
    build_M<<<4096, 256, 0, stream>>>(Wout, attn, Mpack);
    // 8. final: out = v @ M[b]^T + bout  (fp32 out)
    gemm_kernel<2><<<1024, 256, 0, stream>>>(v_bf, Mpack, nullptr, bout, nullptr, nullptr, d_out, nullptr);
}

// Round 2
// 382.113 us; speedup vs baseline: 1.0071x; 1.0071x over previous
//
#include <hip/hip_runtime.h>
#include <hip/hip_bf16.h>
#include <math.h>

using u16 = unsigned short;
using u32 = unsigned int;

typedef __attribute__((ext_vector_type(8))) short s16x8;
typedef __attribute__((ext_vector_type(4))) float f32x4;

#define B_  4
#define L_  8192
#define D_  512
#define H_  8
#define G_  4

// ---------- helpers ----------
__device__ __forceinline__ float bf2f(u16 u) {
    u32 x = ((u32)u) << 16;
    return __uint_as_float(x);
}
__device__ __forceinline__ u16 f2bf(float f) {  // round-to-nearest-even
    u32 x = __float_as_uint(f);
    u32 lsb = (x >> 16) & 1u;
    x += 0x7FFFu + lsb;
    return (u16)(x >> 16);
}
__device__ __forceinline__ void async16(const void* g, void* l) {
    __builtin_amdgcn_global_load_lds((const __attribute__((address_space(1))) u32*)g,
                                     (__attribute__((address_space(3))) u32*)l, 16, 0, 0);
}

// ---------- fused prep: cast x -> bf16 | pack weights | compose offset convs ----------
// blocks [0,16384): cast; [16384,16768): pack (128 per weight); [16768,16771): weff
#define CAST_BLOCKS 16384
#define PACK_BLOCKS 384
__global__ __launch_bounds__(256) void prep_kernel(const float* __restrict__ x,
                                                   u16* __restrict__ x_bf,
                                                   const float* __restrict__ Wq,
                                                   const float* __restrict__ Wk,
                                                   const float* __restrict__ Wv,
                                                   u16* __restrict__ Pq,
                                                   u16* __restrict__ Pk,
                                                   u16* __restrict__ Pv,
                                                   const float* __restrict__ W1,
                                                   const float* __restrict__ b1,
                                                   const float* __restrict__ W2,
                                                   const float* __restrict__ b2,
                                                   float* __restrict__ weff) {
    const int bid = blockIdx.x;
    const int tid = threadIdx.x;
    if (bid < CAST_BLOCKS) {
        // cast fp32 -> bf16, 4 floats/thread
        const int i = bid * 256 + tid;            // < 4194304 exactly
        float4 v = ((const float4*)x)[i];
        ushort4 o;
        o.x = f2bf(v.x); o.y = f2bf(v.y); o.z = f2bf(v.z); o.w = f2bf(v.w);
        ((ushort4*)x_bf)[i] = o;
    } else if (bid < CAST_BLOCKS + PACK_BLOCKS) {
        // pack a 512x512 f32 weight into MFMA B-fragment order (bf16)
        const int pb = bid - CAST_BLOCKS;
        const int wsel = pb >> 7;                  // 0..2
        const int xb = pb & 127;
        const int g = xb * 4 + (tid >> 6);         // 0..511 = cb*16+kc
        const int lane = tid & 63;
        const int cb = g >> 4, kc = g & 15;
        const int q = lane >> 4, fm = lane & 15;
        const float* W = (wsel == 0) ? Wq : (wsel == 1) ? Wk : Wv;
        u16* P = (wsel == 0) ? Pq : (wsel == 1) ? Pk : Pv;
        const float* src = W + (size_t)(cb * 16 + fm) * 512 + kc * 32 + q * 8;
        float4 a = *(const float4*)src;
        float4 b = *(const float4*)(src + 4);
        ushort4 o0, o1;
        o0.x = f2bf(a.x); o0.y = f2bf(a.y); o0.z = f2bf(a.z); o0.w = f2bf(a.w);
        o1.x = f2bf(b.x); o1.y = f2bf(b.y); o1.z = f2bf(b.z); o1.w = f2bf(b.w);
        u16* dst = P + (size_t)g * 512 + lane * 8;
        *(ushort4*)dst = o0;
        *(ushort4*)(dst + 4) = o1;
    } else {
        // compose conv1(128x128x5) + conv2(1x128x1) -> weff (642 floats)
        const int idx = (bid - CAST_BLOCKS - PACK_BLOCKS) * 256 + tid;  // [0,768)
        if (idx < 640) {
            int cin = idx / 5, dk = idx % 5;
            float acc = 0.f;
            for (int c = 0; c < 128; ++c) acc += W2[c] * W1[(c * 128 + cin) * 5 + dk];
            weff[idx] = acc;
        } else if (idx == 640) {
            float s = b2[0];
            for (int c = 0; c < 128; ++c) s += W2[c] * b1[c];
            weff[640] = s;              // composed bias (t>=2)
        } else if (idx == 641) {
            weff[641] = b2[0];          // conv2-pad-only bias (t<2)
        }
    }
}

// ---------- fused offset conv + tanh + grid_sample position precompute ----------
__global__ __launch_bounds__(256) void offsets_kernel(const u16* __restrict__ qT,
                                                      const float* __restrict__ weff,
                                                      int* __restrict__ p0o,
                                                      float* __restrict__ w1o) {
    __shared__ u16 qs[128 * 72];   // 128 ch x 72 l (l from t0-8), 18.4 KB
    __shared__ float wf[642];
    __shared__ float red[4][64];
    const int tid = threadIdx.x;
    const int t0 = blockIdx.x * 64;
    const int bg = blockIdx.y;
    const int b = bg >> 2, g = bg & 3;
    for (int i = tid; i < 642; i += 256) wf[i] = weff[i];
    for (int i = tid; i < 128 * 9; i += 256) {
        const int ch = i / 9, seg = i - ch * 9;
        const int l = t0 - 8 + seg * 8;
        s16x8 val = {0, 0, 0, 0, 0, 0, 0, 0};
        if (l >= 0)
            val = *(const s16x8*)(qT + (size_t)(b * D_ + g * 128 + ch) * L_ + l);
        *(s16x8*)(qs + ch * 72 + seg * 8) = val;
    }
    __syncthreads();
    const int w = tid >> 6, lane = tid & 63;
    float acc = 0.f;
    for (int c = 0; c < 32; ++c) {
        const int ch = w * 32 + c;
        const u16* row = qs + ch * 72 + lane + 4;   // lc = (t-t0)+4+dk
        const float* wr = wf + ch * 5;
        #pragma unroll
        for (int dk = 0; dk < 5; ++dk) acc += wr[dk] * bf2f(row[dk]);
    }
    red[w][lane] = acc;
    __syncthreads();
    if (w == 0) {
        const float s = red[0][lane] + red[1][lane] + red[2][lane] + red[3][lane];
        const int t = t0 + lane;
        const float o2 = (t >= 2) ? (s + wf[640]) : wf[641];
        const double offv = tanh((double)o2) * 5.0;
        const double vg  = (double)t + offv;
        const double gg  = 2.0 * vg / 8195.0 - 1.0;          // n-1 = L+3 = 8195
        const double pos = ((gg + 1.0) * 8192.0 - 1.0) * 0.5;
        const double p0d = floor(pos);
        p0o[(size_t)bg * L_ + t] = (int)p0d;
        w1o[(size_t)bg * L_ + t] = (float)(pos - p0d);
    }
}

// ---------- bilinear gather from bf16 x: 8 d-channels per thread (16B loads) ----------
__global__ __launch_bounds__(256) void sample_bf16(const u16* __restrict__ xb,
                                                   const int* __restrict__ p0i,
                                                   const float* __restrict__ w1f,
                                                   u16* __restrict__ xs) {
    const size_t idx = (size_t)blockIdx.x * 256 + threadIdx.x;   // B*L*64
    const int d8 = (int)(idx & 63);             // 8-channel group
    const int t = (int)((idx >> 6) & 8191);
    const int b = (int)(idx >> 19);
    const int g = d8 >> 4;
    const size_t og = (size_t)(b * 4 + g) * L_ + t;
    const int p0 = p0i[og];
    const float w1 = w1f[og];
    const float w0 = 1.f - w1;
    const int p1 = p0 + 1;
    s16x8 a = {0, 0, 0, 0, 0, 0, 0, 0}, c = {0, 0, 0, 0, 0, 0, 0, 0};
    if (p0 >= 0 && p0 < L_) a = *(const s16x8*)(xb + ((size_t)b * L_ + p0) * D_ + d8 * 8);
    if (p1 >= 0 && p1 < L_) c = *(const s16x8*)(xb + ((size_t)b * L_ + p1) * D_ + d8 * 8);
    u16 o[8];
    #pragma unroll
    for (int j = 0; j < 8; ++j)
        o[j] = f2bf(bf2f(((const u16*)&a)[j]) * w0 + bf2f(((const u16*)&c)[j]) * w1);
    *(s16x8*)(xs + idx * 8) = *(const s16x8*)o;
}

// ---------- fallback: bilinear gather from fp32 x, 4 d-channels per thread ----------
__global__ __launch_bounds__(256) void sample_f32(const float* __restrict__ x,
                                                  const int* __restrict__ p0i,
                                                  const float* __restrict__ w1f,
                                                  u16* __restrict__ xs) {
    const size_t idx4 = (size_t)blockIdx.x * 256 + threadIdx.x;   // B*L*D/4
    const int d4 = (int)(idx4 & 127);           // 4-channel group
    const int t = (int)((idx4 >> 7) & 8191);
    const int b = (int)(idx4 >> 20);
    const int g = d4 >> 5;
    const size_t og = (size_t)(b * 4 + g) * L_ + t;
    const int p0 = p0i[og];
    const float w1 = w1f[og];
    const float w0 = 1.f - w1;
    const int p1 = p0 + 1;
    float4 v0 = {0.f, 0.f, 0.f, 0.f}, v1 = {0.f, 0.f, 0.f, 0.f};
    if (p0 >= 0 && p0 < L_) v0 = *(const float4*)(x + ((size_t)b * L_ + p0) * D_ + d4 * 4);
    if (p1 >= 0 && p1 < L_) v1 = *(const float4*)(x + ((size_t)b * L_ + p1) * D_ + d4 * 4);
    ushort4 o;
    o.x = f2bf(v0.x * w0 + v1.x * w1);
    o.y = f2bf(v0.y * w0 + v1.y * w1);
    o.z = f2bf(v0.z * w0 + v1.z * w1);
    o.w = f2bf(v0.w * w0 + v1.w * w1);
    ((ushort4*)xs)[idx4] = o;
}

// ---------- MFMA GEMM: block-cooperative 128x128 tile, 2-phase double-buffered A ----
// A tile [128][32] bf16 staged block-shared via global_load_lds (XOR-swizzled pair),
// double-buffered (16 KB LDS). B read per-wave direct from packed weights into regs,
// issued BEFORE the A-DMAs so the compiler's derived vmcnt keeps DMAs in flight.
// MODE 0: q    -> transposed bf16 out (qT)
// MODE 1: k|v  -> sel=0: transposed bf16 (kT); sel=1: row-major bf16 + rel (v). grid 2x.
// MODE 2: final-> row-major fp32 out, P indexed per-batch
template <int MODE>
__global__ __launch_bounds__(256) void gemm_kernel(const u16* __restrict__ A,
                                                   const u16* __restrict__ P0,
                                                   const u16* __restrict__ P1,
                                                   const float* __restrict__ bias0,
                                                   const float* __restrict__ bias1,
                                                   const float* __restrict__ rel,
                                                   void* __restrict__ out0,
                                                   void* __restrict__ out1) {
    __shared__ __align__(16) short abuf[2][128 * 32];   // 2 x 8 KB double buffer
    const int tid = threadIdx.x;
    const int wave = tid >> 6, lane = tid & 63;
    const int bid = blockIdx.x;
    const int xcd = bid & 7;
    const int kk_ = bid >> 3;
    int r0, c0, sel;
    if (MODE == 1) { r0 = (xcd * 32 + (kk_ >> 3)) * 128; sel = (kk_ >> 2) & 1; c0 = (kk_ & 3) * 128; }
    else           { r0 = (xcd * 32 + (kk_ >> 2)) * 128; sel = 0;              c0 = (kk_ & 3) * 128; }
    const u16* P = (MODE == 1 && sel) ? P1 : P0;
    if (MODE == 2) P += (size_t)(r0 >> 13) * 262144;       // per-batch packed M
    const float* bias = (MODE == 1 && sel) ? bias1 : bias0;
    void* out = (MODE == 1 && sel) ? out1 : out0;

    const int wm = (wave >> 1) * 64, wn = (wave & 1) * 64;
    // staging: wave w covers LDS rows [w*32, w*32+32); srow/scol = verified swizzle pair
    const int srow = lane >> 2;
    const int scol = ((lane & 3) ^ ((srow >> 1) & 3)) * 8;   // XOR-swizzled 16B block (source side)
    const u16* gA = A + (size_t)(r0 + wave * 32) * D_ + scol;
    const int cbase = (c0 + wn) >> 4;

    f32x4 acc[4][4];
    #pragma unroll
    for (int mi = 0; mi < 4; ++mi)
        #pragma unroll
        for (int ni = 0; ni < 4; ++ni) acc[mi][ni] = (f32x4){0.f, 0.f, 0.f, 0.f};

    const int fm = lane & 15;
    const int sblk = ((lane >> 4) ^ ((fm >> 1) & 3)) * 8;    // inverse swizzle (read side)

    s16x8 bfrag[4];

    auto stageA = [&](int bsel, int it) {
        const int k0 = it * 32;
        #pragma unroll
        for (int j = 0; j < 2; ++j)
            async16(gA + (size_t)(j * 16 + srow) * D_ + k0,
                    &abuf[bsel][wave * 1024 + j * 512]);
    };
    auto loadB = [&](int it) {
        #pragma unroll
        for (int ni = 0; ni < 4; ++ni)
            bfrag[ni] = *(const s16x8*)(P + ((size_t)((cbase + ni) * 16 + it) * 64 + lane) * 8);
    };

    stageA(0, 0);
    __syncthreads();

    #pragma unroll
    for (int it = 0; it < 16; ++it) {
        const int cur = it & 1;
        loadB(it);                         // 4 global 16B loads (oldest vm ops)
        if (it < 15) stageA(cur ^ 1, it + 1);   // 2 DMAs stay in flight past B-wait
        s16x8 af[4];
        #pragma unroll
        for (int mi = 0; mi < 4; ++mi)
            af[mi] = *(const s16x8*)(&abuf[cur][(wm + mi * 16 + fm) * 32 + sblk]);
        #pragma unroll
        for (int mi = 0; mi < 4; ++mi)
            #pragma unroll
            for (int ni = 0; ni < 4; ++ni)
                acc[mi][ni] = __builtin_amdgcn_mfma_f32_16x16x32_bf16(af[mi], bfrag[ni], acc[mi][ni], 0, 0, 0);
        __syncthreads();                   // drains DMAs for buf cur^1 before next read
    }

    // epilogue: D layout col = lane&15, row = (lane>>4)*4 + reg
    const int fn = lane & 15;
    const int q4 = (lane >> 4) * 4;
    const bool transposed = (MODE == 0) || (MODE == 1 && sel == 0);
    #pragma unroll
    for (int mi = 0; mi < 4; ++mi) {
        #pragma unroll
        for (int ni = 0; ni < 4; ++ni) {
            const int c = c0 + wn + ni * 16 + fn;
            const float bsum = bias[c];
            if (MODE == 2) {
                #pragma unroll
                for (int rg = 0; rg < 4; ++rg) {
                    const int r = r0 + wm + mi * 16 + q4 + rg;
                    ((float*)out)[(size_t)r * D_ + c] = acc[mi][ni][rg] + bsum;
                }
            } else if (transposed) {
                const int r_ = r0 + wm + mi * 16 + q4;   // 4 consecutive rows
                const int bb = r_ >> 13;
                const int l  = r_ & (L_ - 1);
                ushort4 o;
                o.x = f2bf(acc[mi][ni][0] + bsum);
                o.y = f2bf(acc[mi][ni][1] + bsum);
                o.z = f2bf(acc[mi][ni][2] + bsum);
                o.w = f2bf(acc[mi][ni][3] + bsum);
                *(ushort4*)((u16*)out + (size_t)(bb * D_ + c) * L_ + l) = o;
            } else {
                const int r_ = r0 + wm + mi * 16 + q4;
                const int l  = r_ & (L_ - 1);
                const float4 rl = *(const float4*)(rel + (size_t)c * L_ + l);
                ((u16*)out)[(size_t)(r_ + 0) * D_ + c] = f2bf(acc[mi][ni][0] + bsum + rl.x);
                ((u16*)out)[(size_t)(r_ + 1) * D_ + c] = f2bf(acc[mi][ni][1] + bsum + rl.y);
                ((u16*)out)[(size_t)(r_ + 2) * D_ + c] = f2bf(acc[mi][ni][2] + bsum + rl.z);
                ((u16*)out)[(size_t)(r_ + 3) * D_ + c] = f2bf(acc[mi][ni][3] + bsum + rl.w);
            }
        }
    }
}

// ---------- channel-attention scores via MFMA, split-K partials ----------
__global__ __launch_bounds__(256) void scores_partial(const u16* __restrict__ qT,
                                                      const u16* __restrict__ kT,
                                                      float* __restrict__ part) {
    __shared__ u16 qs[64 * 136];
    __shared__ u16 ks[64 * 136];
    const int chunk = blockIdx.x;   // 0..15, 512 l each
    const int bh = blockIdx.y;      // 0..31
    const int b = bh >> 3, h = bh & 7;
    const int tid = threadIdx.x;
    const int wave = tid >> 6, lane = tid & 63;
    const int wr = (wave >> 1) * 32;
    const int wc = (wave & 1) * 32;
    f32x4 acc[2][2];
    #pragma unroll
    for (int mi = 0; mi < 2; ++mi)
        #pragma unroll
        for (int ni = 0; ni < 2; ++ni) acc[mi][ni] = (f32x4){0.f, 0.f, 0.f, 0.f};
    const size_t base = (size_t)(b * D_ + h * 64) * L_;
    const int m = lane & 15, q = lane >> 4;
    for (int iter = 0; iter < 4; ++iter) {
        const int l0 = chunk * 512 + iter * 128;
        __syncthreads();
        for (int i = tid; i < 1024; i += 256) {
            const int lb = i & 15, ch = i >> 4;
            const size_t gidx = base + (size_t)ch * L_ + l0 + lb * 8;
            *(s16x8*)(qs + ch * 136 + lb * 8) = *(const s16x8*)(qT + gidx);
            *(s16x8*)(ks + ch * 136 + lb * 8) = *(const s16x8*)(kT + gidx);
        }
        __syncthreads();
        #pragma unroll
        for (int kst = 0; kst < 4; ++kst) {
            const int kk = kst * 32 + q * 8;
            s16x8 af[2], bfr[2];
            af[0]  = *(const s16x8*)(qs + (wr + m) * 136 + kk);
            af[1]  = *(const s16x8*)(qs + (wr + 16 + m) * 136 + kk);
            bfr[0] = *(const s16x8*)(ks + (wc + m) * 136 + kk);
            bfr[1] = *(const s16x8*)(ks + (wc + 16 + m) * 136 + kk);
            #pragma unroll
            for (int mi = 0; mi < 2; ++mi)
                #pragma unroll
                for (int ni = 0; ni < 2; ++ni)
                    acc[mi][ni] = __builtin_amdgcn_mfma_f32_16x16x32_bf16(af[mi], bfr[ni], acc[mi][ni], 0, 0, 0);
        }
    }
    float* dst = part + (size_t)(bh * 16 + chunk) * 4096;
    const int q4 = (lane >> 4) * 4;
    #pragma unroll
    for (int mi = 0; mi < 2; ++mi) {
        #pragma unroll
        for (int ni = 0; ni < 2; ++ni) {
            const int j = wc + ni * 16 + m;
            #pragma unroll
            for (int rg = 0; rg < 4; ++rg) {
                const int i = wr + mi * 16 + q4 + rg;
                dst[i * 64 + j] = acc[mi][ni][rg];
            }
        }
    }
}

// ---------- sum partials, scale, softmax over last dim ----------
__global__ __launch_bounds__(256) void softmax_kernel(const float* __restrict__ part,
                                                      float* __restrict__ attn) {
    const int tid = threadIdx.x;
    const int wave = tid >> 6, lane = tid & 63;
    const int row = blockIdx.x * 4 + wave;
    const int bh = row >> 6, i = row & 63;
    float s = 0.f;
    #pragma unroll
    for (int c = 0; c < 16; ++c) s += part[((size_t)(bh * 16 + c)) * 4096 + i * 64 + lane];
    s *= 0.04419417382415922f;               // 512^-0.5
    float m = s;
    for (int off = 32; off > 0; off >>= 1) m = fmaxf(m, __shfl_xor(m, off));
    float e = expf(s - m);
    float sum = e;
    for (int off = 32; off > 0; off >>= 1) sum += __shfl_xor(sum, off);
    attn[(size_t)bh * 4096 + i * 64 + lane] = e / sum;
}

// ---------- M[b] = Wout * blockdiag(attn[b]) written in packed B-fragment order ----
__global__ __launch_bounds__(256) void build_M(const float* __restrict__ Wout,
                                               const float* __restrict__ attn,
                                               u16* __restrict__ Mpack) {
    const int idx = blockIdx.x * 256 + threadIdx.x;   // b*512*512 + o*512 + col
    const int col = idx & 511;                        // k (v-channel)
    const int o = (idx >> 9) & 511;                   // out-channel (GEMM col c)
    const int b = idx >> 18;
    const int h = col >> 6, j0 = col & 63;
    const float* wr = Wout + o * 512 + h * 64;
    const float* ar = attn + (size_t)(b * H_ + h) * 4096 + j0;
    float s = 0.f;
    #pragma unroll 8
    for (int i = 0; i < 64; ++i) s += wr[i] * ar[i * 64];
    const int cb = o >> 4, fm = o & 15;
    const int kc = col >> 5, q = (col >> 3) & 3, j = col & 7;
    Mpack[(size_t)b * 262144 + ((size_t)(cb * 16 + kc) * 64 + q * 16 + fm) * 8 + j] = f2bf(s);
}

extern "C" void kernel_launch(void* const* d_in, const int* in_sizes, int n_in,
                              void* d_out, int out_size, void* d_ws, size_t ws_size,
                              hipStream_t stream) {
    const float* x    = (const float*)d_in[0];
    const float* Wq   = (const float*)d_in[1];
    const float* bq   = (const float*)d_in[2];
    const float* Wk   = (const float*)d_in[3];
    const float* bk   = (const float*)d_in[4];
    const float* Wv   = (const float*)d_in[5];
    const float* bv   = (const float*)d_in[6];
    const float* Wo1  = (const float*)d_in[7];
    const float* bo1  = (const float*)d_in[8];
    const float* Wo2  = (const float*)d_in[9];
    const float* bo2  = (const float*)d_in[10];
    const float* rel  = (const float*)d_in[11];
    const float* Wout = (const float*)d_in[12];
    const float* bout = (const float*)d_in[13];

    char* ws = (char*)d_ws;
    const size_t MB = 1024ull * 1024ull;
    const bool big = ws_size >= 165ull * MB;   // bf16-sample path needs ~163.2 MB

    u16* x_bf = (u16*)(ws);                    // 32 MB
    u16* qT   = (u16*)(ws + 32 * MB);          // 32 MB, [b*D+ch][l]
    u16* kT   = (u16*)(ws + 64 * MB);          // 32 MB, [b*D+ch][l]
    u16* v_bf = (u16*)(ws + 96 * MB);          // 32 MB, row-major

    u16*   xs;     // sampled x (bf16 row-major), A-input of gemm_kv
    u16*   Pq; u16* Pk; u16* Pv;
    float* weff; int* p0i; float* w1f;
    float* part; float* attn; u16* Mpack;

    if (big) {
        // xs lives at 128..160 MB while needed (disp 5-6); part/attn/Mpack
        // reuse the same window afterwards (written only at disp 7+, xs dead).
        xs    = (u16*)(ws + 128 * MB);                         // 32 MB
        part  = (float*)(ws + 128 * MB);                       // 8 MB (after xs dead)
        attn  = (float*)((char*)part + 8 * MB);                // 512 KB
        Mpack = (u16*)((char*)attn + 524288);                  // 2 MB
        Pq    = (u16*)(ws + 160 * MB);                         // 512 KB each
        Pk    = Pq + 262144;
        Pv    = Pk + 262144;
        weff  = (float*)(ws + 162 * MB);                       // 642 floats
        p0i   = (int*)(ws + 162 * MB + 65536);                 // 512 KB
        w1f   = (float*)((char*)p0i + 524288);                 // 512 KB
    } else {
        // legacy layout: xs overwrites x_bf (fp32 sampling; x_bf dead after gemm_q)
        xs    = x_bf;
        Pq    = (u16*)(ws + 128 * MB);
        Pk    = Pq + 262144;
        Pv    = Pk + 262144;
        weff  = (float*)(ws + 130 * MB);
        p0i   = (int*)(ws + 130 * MB + 65536);
        w1f   = (float*)((char*)p0i + 524288);
        part  = (float*)((char*)w1f + 524288);
        attn  = (float*)((char*)part + 8 * MB);
        Mpack = (u16*)((char*)attn + 524288);
    }

    // 1. fused prep: cast x -> bf16, pack Wq/Wk/Wv, compose offset convs
    prep_kernel<<<CAST_BLOCKS + PACK_BLOCKS + 3, 256, 0, stream>>>(
        x, x_bf, Wq, Wk, Wv, Pq, Pk, Pv, Wo1, bo1, Wo2, bo2, weff);
    // 2. q = x @ Wq^T  (stored transposed)
    gemm_kernel<0><<<1024, 256, 0, stream>>>(x_bf, Pq, nullptr, bq, nullptr, nullptr, (void*)qT, nullptr);
    // 3. offsets -> sampling positions (reads qT)
    offsets_kernel<<<dim3(128, 16), 256, 0, stream>>>(qT, weff, p0i, w1f);
    // 4. bilinear sample
    if (big) sample_bf16<<<8192, 256, 0, stream>>>(x_bf, p0i, w1f, xs);
    else     sample_f32<<<16384, 256, 0, stream>>>(x, p0i, w1f, xs);
    // 5. k (transposed) + v (row-major + rel) in ONE dispatch
    gemm_kernel<1><<<2048, 256, 0, stream>>>(xs, Pk, Pv, bk, bv, rel, (void*)kT, (void*)v_bf);
    // 6. scores (MFMA) + softmax
    scores_partial<<<dim3(16, 32), 256, 0, stream>>>(qT, kT, part);
    softmax_kernel<<<512, 256, 0, stream>>>(part, attn);
    // 7. fold attn into output projection (packed layout)
    build_M<<<4096, 256, 0, stream>>>(Wout, attn, Mpack);
    // 8. final: out = v @ M[b]^T + bout  (fp32 out)
    gemm_kernel<2><<<1024, 256, 0, stream>>>(v_bf, Mpack, nullptr, bout, nullptr, nullptr, d_out, nullptr);
}

// Round 3
// 375.900 us; speedup vs baseline: 1.0237x; 1.0165x over previous
//
#include <hip/hip_runtime.h>
#include <hip/hip_bf16.h>
#include <math.h>

using u16 = unsigned short;
using u32 = unsigned int;

typedef __attribute__((ext_vector_type(8))) short s16x8;
typedef __attribute__((ext_vector_type(4))) float f32x4;

#define B_  4
#define L_  8192
#define D_  512
#define H_  8
#define G_  4

// ---------- helpers ----------
__device__ __forceinline__ float bf2f(u16 u) {
    u32 x = ((u32)u) << 16;
    return __uint_as_float(x);
}
__device__ __forceinline__ u16 f2bf(float f) {  // round-to-nearest-even
    u32 x = __float_as_uint(f);
    u32 lsb = (x >> 16) & 1u;
    x += 0x7FFFu + lsb;
    return (u16)(x >> 16);
}
__device__ __forceinline__ void async16(const void* g, void* l) {
    __builtin_amdgcn_global_load_lds((const __attribute__((address_space(1))) u32*)g,
                                     (__attribute__((address_space(3))) u32*)l, 16, 0, 0);
}
// s_waitcnt immediates (gfx9): vmcnt low4 bits[3:0], high2 bits[15:14]; exp [6:4]; lgkm [11:8]
#define WAIT_VM8   0x0F78
#define WAIT_VM4   0x0F74
#define WAIT_VM0   0x0F70

// ---------- fused prep: cast x -> bf16 | pack weights | compose offset convs ----------
// blocks [0,16384): cast; [16384,16768): pack (128 per weight); [16768,16771): weff
#define CAST_BLOCKS 16384
#define PACK_BLOCKS 384
__global__ __launch_bounds__(256) void prep_kernel(const float* __restrict__ x,
                                                   u16* __restrict__ x_bf,
                                                   const float* __restrict__ Wq,
                                                   const float* __restrict__ Wk,
                                                   const float* __restrict__ Wv,
                                                   u16* __restrict__ Pq,
                                                   u16* __restrict__ Pk,
                                                   u16* __restrict__ Pv,
                                                   const float* __restrict__ W1,
                                                   const float* __restrict__ b1,
                                                   const float* __restrict__ W2,
                                                   const float* __restrict__ b2,
                                                   float* __restrict__ weff) {
    const int bid = blockIdx.x;
    const int tid = threadIdx.x;
    if (bid < CAST_BLOCKS) {
        // cast fp32 -> bf16, 4 floats/thread
        const int i = bid * 256 + tid;            // < 4194304 exactly
        float4 v = ((const float4*)x)[i];
        ushort4 o;
        o.x = f2bf(v.x); o.y = f2bf(v.y); o.z = f2bf(v.z); o.w = f2bf(v.w);
        ((ushort4*)x_bf)[i] = o;
    } else if (bid < CAST_BLOCKS + PACK_BLOCKS) {
        // pack a 512x512 f32 weight into MFMA B-fragment order (bf16)
        const int pb = bid - CAST_BLOCKS;
        const int wsel = pb >> 7;                  // 0..2
        const int xb = pb & 127;
        const int g = xb * 4 + (tid >> 6);         // 0..511 = cb*16+kc
        const int lane = tid & 63;
        const int cb = g >> 4, kc = g & 15;
        const int q = lane >> 4, fm = lane & 15;
        const float* W = (wsel == 0) ? Wq : (wsel == 1) ? Wk : Wv;
        u16* P = (wsel == 0) ? Pq : (wsel == 1) ? Pk : Pv;
        const float* src = W + (size_t)(cb * 16 + fm) * 512 + kc * 32 + q * 8;
        float4 a = *(const float4*)src;
        float4 b = *(const float4*)(src + 4);
        ushort4 o0, o1;
        o0.x = f2bf(a.x); o0.y = f2bf(a.y); o0.z = f2bf(a.z); o0.w = f2bf(a.w);
        o1.x = f2bf(b.x); o1.y = f2bf(b.y); o1.z = f2bf(b.z); o1.w = f2bf(b.w);
        u16* dst = P + (size_t)g * 512 + lane * 8;
        *(ushort4*)dst = o0;
        *(ushort4*)(dst + 4) = o1;
    } else {
        // compose conv1(128x128x5) + conv2(1x128x1) -> weff (642 floats)
        const int idx = (bid - CAST_BLOCKS - PACK_BLOCKS) * 256 + tid;  // [0,768)
        if (idx < 640) {
            int cin = idx / 5, dk = idx % 5;
            float acc = 0.f;
            for (int c = 0; c < 128; ++c) acc += W2[c] * W1[(c * 128 + cin) * 5 + dk];
            weff[idx] = acc;
        } else if (idx == 640) {
            float s = b2[0];
            for (int c = 0; c < 128; ++c) s += W2[c] * b1[c];
            weff[640] = s;              // composed bias (t>=2)
        } else if (idx == 641) {
            weff[641] = b2[0];          // conv2-pad-only bias (t<2)
        }
    }
}

// ---------- fused offset conv + tanh + grid_sample position precompute ----------
__global__ __launch_bounds__(256) void offsets_kernel(const u16* __restrict__ qT,
                                                      const float* __restrict__ weff,
                                                      int* __restrict__ p0o,
                                                      float* __restrict__ w1o) {
    __shared__ u16 qs[128 * 72];   // 128 ch x 72 l (l from t0-8), 18.4 KB
    __shared__ float wf[642];
    __shared__ float red[4][64];
    const int tid = threadIdx.x;
    const int t0 = blockIdx.x * 64;
    const int bg = blockIdx.y;
    const int b = bg >> 2, g = bg & 3;
    for (int i = tid; i < 642; i += 256) wf[i] = weff[i];
    for (int i = tid; i < 128 * 9; i += 256) {
        const int ch = i / 9, seg = i - ch * 9;
        const int l = t0 - 8 + seg * 8;
        s16x8 val = {0, 0, 0, 0, 0, 0, 0, 0};
        if (l >= 0)
            val = *(const s16x8*)(qT + (size_t)(b * D_ + g * 128 + ch) * L_ + l);
        *(s16x8*)(qs + ch * 72 + seg * 8) = val;
    }
    __syncthreads();
    const int w = tid >> 6, lane = tid & 63;
    float acc = 0.f;
    for (int c = 0; c < 32; ++c) {
        const int ch = w * 32 + c;
        const u16* row = qs + ch * 72 + lane + 4;   // lc = (t-t0)+4+dk
        const float* wr = wf + ch * 5;
        #pragma unroll
        for (int dk = 0; dk < 5; ++dk) acc += wr[dk] * bf2f(row[dk]);
    }
    red[w][lane] = acc;
    __syncthreads();
    if (w == 0) {
        const float s = red[0][lane] + red[1][lane] + red[2][lane] + red[3][lane];
        const int t = t0 + lane;
        const float o2 = (t >= 2) ? (s + wf[640]) : wf[641];
        const double offv = tanh((double)o2) * 5.0;
        const double vg  = (double)t + offv;
        const double gg  = 2.0 * vg / 8195.0 - 1.0;          // n-1 = L+3 = 8195
        const double pos = ((gg + 1.0) * 8192.0 - 1.0) * 0.5;
        const double p0d = floor(pos);
        p0o[(size_t)bg * L_ + t] = (int)p0d;
        w1o[(size_t)bg * L_ + t] = (float)(pos - p0d);
    }
}

// ---------- bilinear gather from bf16 x: 8 d-channels per thread (16B loads) ----------
__global__ __launch_bounds__(256) void sample_bf16(const u16* __restrict__ xb,
                                                   const int* __restrict__ p0i,
                                                   const float* __restrict__ w1f,
                                                   u16* __restrict__ xs) {
    const size_t idx = (size_t)blockIdx.x * 256 + threadIdx.x;   // B*L*64
    const int d8 = (int)(idx & 63);             // 8-channel group
    const int t = (int)((idx >> 6) & 8191);
    const int b = (int)(idx >> 19);
    const int g = d8 >> 4;
    const size_t og = (size_t)(b * 4 + g) * L_ + t;
    const int p0 = p0i[og];
    const float w1 = w1f[og];
    const float w0 = 1.f - w1;
    const int p1 = p0 + 1;
    s16x8 a = {0, 0, 0, 0, 0, 0, 0, 0}, c = {0, 0, 0, 0, 0, 0, 0, 0};
    if (p0 >= 0 && p0 < L_) a = *(const s16x8*)(xb + ((size_t)b * L_ + p0) * D_ + d8 * 8);
    if (p1 >= 0 && p1 < L_) c = *(const s16x8*)(xb + ((size_t)b * L_ + p1) * D_ + d8 * 8);
    u16 o[8];
    #pragma unroll
    for (int j = 0; j < 8; ++j)
        o[j] = f2bf(bf2f(((const u16*)&a)[j]) * w0 + bf2f(((const u16*)&c)[j]) * w1);
    *(s16x8*)(xs + idx * 8) = *(const s16x8*)o;
}

// ---------- fallback: bilinear gather from fp32 x, 4 d-channels per thread ----------
__global__ __launch_bounds__(256) void sample_f32(const float* __restrict__ x,
                                                  const int* __restrict__ p0i,
                                                  const float* __restrict__ w1f,
                                                  u16* __restrict__ xs) {
    const size_t idx4 = (size_t)blockIdx.x * 256 + threadIdx.x;   // B*L*D/4
    const int d4 = (int)(idx4 & 127);           // 4-channel group
    const int t = (int)((idx4 >> 7) & 8191);
    const int b = (int)(idx4 >> 20);
    const int g = d4 >> 5;
    const size_t og = (size_t)(b * 4 + g) * L_ + t;
    const int p0 = p0i[og];
    const float w1 = w1f[og];
    const float w0 = 1.f - w1;
    const int p1 = p0 + 1;
    float4 v0 = {0.f, 0.f, 0.f, 0.f}, v1 = {0.f, 0.f, 0.f, 0.f};
    if (p0 >= 0 && p0 < L_) v0 = *(const float4*)(x + ((size_t)b * L_ + p0) * D_ + d4 * 4);
    if (p1 >= 0 && p1 < L_) v1 = *(const float4*)(x + ((size_t)b * L_ + p1) * D_ + d4 * 4);
    ushort4 o;
    o.x = f2bf(v0.x * w0 + v1.x * w1);
    o.y = f2bf(v0.y * w0 + v1.y * w1);
    o.z = f2bf(v0.z * w0 + v1.z * w1);
    o.w = f2bf(v0.w * w0 + v1.w * w1);
    ((ushort4*)xs)[idx4] = o;
}

// ---------- MFMA GEMM: 128x128 tile, 4-slot deep pipeline, counted vmcnt ----------
// A tile [128][32] and B tile (8 cb-chunks, fragment order) both staged via
// global_load_lds into 4 LDS slots. Per iter: raw s_barrier -> ds_read ->
// reissue slot (it+3)&3 for step it+3 -> 16 MFMA -> s_waitcnt vmcnt(8) ->
// s_barrier. vmcnt NEVER drains to 0 in steady state (T4): 8 DMAs (2 future
// stages) stay in flight across barriers. Cross-wave safety: counted-wait-
// then-barrier => all waves' 3-iter-old DMAs landed before any wave reads;
// reissue targets the slot read LAST iter (all reads completed before the
// barrier we just passed).
// MODE 0: q    -> transposed bf16 out (qT)
// MODE 1: k|v  -> sel=0: transposed bf16 (kT); sel=1: row-major bf16 + rel (v). grid 2x.
// MODE 2: final-> row-major fp32 out, P indexed per-batch
template <int MODE>
__global__ __launch_bounds__(256) void gemm_kernel(const u16* __restrict__ A,
                                                   const u16* __restrict__ P0,
                                                   const u16* __restrict__ P1,
                                                   const float* __restrict__ bias0,
                                                   const float* __restrict__ bias1,
                                                   const float* __restrict__ rel,
                                                   void* __restrict__ out0,
                                                   void* __restrict__ out1) {
    __shared__ __align__(16) short abuf[4][128 * 32];   // 4 x 8 KB A slots
    __shared__ __align__(16) short bbuf[4][128 * 32];   // 4 x 8 KB B slots (8 cb x 1KB)
    const int tid = threadIdx.x;
    const int wave = tid >> 6, lane = tid & 63;
    const int bid = blockIdx.x;
    const int xcd = bid & 7;
    const int kk_ = bid >> 3;
    int r0, c0, sel;
    if (MODE == 1) { r0 = (xcd * 32 + (kk_ >> 3)) * 128; sel = (kk_ >> 2) & 1; c0 = (kk_ & 3) * 128; }
    else           { r0 = (xcd * 32 + (kk_ >> 2)) * 128; sel = 0;              c0 = (kk_ & 3) * 128; }
    const u16* P = (MODE == 1 && sel) ? P1 : P0;
    if (MODE == 2) P += (size_t)(r0 >> 13) * 262144;       // per-batch packed M
    const float* bias = (MODE == 1 && sel) ? bias1 : bias0;
    void* out = (MODE == 1 && sel) ? out1 : out0;

    const int wm = (wave >> 1) * 64, wn = (wave & 1) * 64;
    // A staging: wave w covers LDS rows [w*32, w*32+32); verified swizzle pair
    const int srow = lane >> 2;
    const int scol = ((lane & 3) ^ ((srow >> 1) & 3)) * 8;   // XOR swizzle (source side)
    const u16* gA = A + (size_t)(r0 + wave * 32) * D_ + scol;
    const int cb0 = c0 >> 4;                                 // block's base cb (8 total)

    f32x4 acc[4][4];
    #pragma unroll
    for (int mi = 0; mi < 4; ++mi)
        #pragma unroll
        for (int ni = 0; ni < 4; ++ni) acc[mi][ni] = (f32x4){0.f, 0.f, 0.f, 0.f};

    const int fm = lane & 15;
    const int sblk = ((lane >> 4) ^ ((fm >> 1) & 3)) * 8;    // inverse swizzle (read side)

    // stage A (2 DMAs) + B (2 DMAs) for K-step `it` into LDS slot `slot`.
    // DMA dest is wave-uniform; HW adds lane*16B.
    auto stageAB = [&](int slot, int it) {
        const int k0 = it * 32;
        #pragma unroll
        for (int j = 0; j < 2; ++j)
            async16(gA + (size_t)(j * 16 + srow) * D_ + k0,
                    &abuf[slot][wave * 1024 + j * 512]);
        #pragma unroll
        for (int j = 0; j < 2; ++j)
            async16(P + ((size_t)((cb0 + wave * 2 + j) * 16 + it) * 64 + lane) * 8,
                    &bbuf[slot][(wave * 2 + j) * 512]);
    };

    stageAB(0, 0); stageAB(1, 1); stageAB(2, 2);   // 12 DMAs in flight
    __builtin_amdgcn_s_waitcnt(WAIT_VM8);           // slot0 landed; slots 1,2 in flight
    __builtin_amdgcn_s_barrier();

    #pragma unroll
    for (int it = 0; it < 16; ++it) {
        const int slot = it & 3;
        s16x8 af[4], bf[4];
        #pragma unroll
        for (int mi = 0; mi < 4; ++mi)
            af[mi] = *(const s16x8*)(&abuf[slot][(wm + mi * 16 + fm) * 32 + sblk]);
        #pragma unroll
        for (int ni = 0; ni < 4; ++ni)
            bf[ni] = *(const s16x8*)(&bbuf[slot][((wave & 1) * 4 + ni) * 512 + lane * 8]);
        if (it < 13) stageAB((it + 3) & 3, it + 3);   // reissue slot read LAST iter
        #pragma unroll
        for (int mi = 0; mi < 4; ++mi)
            #pragma unroll
            for (int ni = 0; ni < 4; ++ni)
                acc[mi][ni] = __builtin_amdgcn_mfma_f32_16x16x32_bf16(af[mi], bf[ni], acc[mi][ni], 0, 0, 0);
        if (it < 15) {
            if (it <= 12)      __builtin_amdgcn_s_waitcnt(WAIT_VM8);   // next slot landed
            else if (it == 13) __builtin_amdgcn_s_waitcnt(WAIT_VM4);
            else               __builtin_amdgcn_s_waitcnt(WAIT_VM0);   // it == 14
            __builtin_amdgcn_s_barrier();
        }
    }

    // epilogue: D layout col = lane&15, row = (lane>>4)*4 + reg
    const int fn = lane & 15;
    const int q4 = (lane >> 4) * 4;
    const bool transposed = (MODE == 0) || (MODE == 1 && sel == 0);
    #pragma unroll
    for (int mi = 0; mi < 4; ++mi) {
        #pragma unroll
        for (int ni = 0; ni < 4; ++ni) {
            const int c = c0 + wn + ni * 16 + fn;
            const float bsum = bias[c];
            if (MODE == 2) {
                #pragma unroll
                for (int rg = 0; rg < 4; ++rg) {
                    const int r = r0 + wm + mi * 16 + q4 + rg;
                    ((float*)out)[(size_t)r * D_ + c] = acc[mi][ni][rg] + bsum;
                }
            } else if (transposed) {
                const int r_ = r0 + wm + mi * 16 + q4;   // 4 consecutive rows
                const int bb = r_ >> 13;
                const int l  = r_ & (L_ - 1);
                ushort4 o;
                o.x = f2bf(acc[mi][ni][0] + bsum);
                o.y = f2bf(acc[mi][ni][1] + bsum);
                o.z = f2bf(acc[mi][ni][2] + bsum);
                o.w = f2bf(acc[mi][ni][3] + bsum);
                *(ushort4*)((u16*)out + (size_t)(bb * D_ + c) * L_ + l) = o;
            } else {
                const int r_ = r0 + wm + mi * 16 + q4;
                const int l  = r_ & (L_ - 1);
                const float4 rl = *(const float4*)(rel + (size_t)c * L_ + l);
                ((u16*)out)[(size_t)(r_ + 0) * D_ + c] = f2bf(acc[mi][ni][0] + bsum + rl.x);
                ((u16*)out)[(size_t)(r_ + 1) * D_ + c] = f2bf(acc[mi][ni][1] + bsum + rl.y);
                ((u16*)out)[(size_t)(r_ + 2) * D_ + c] = f2bf(acc[mi][ni][2] + bsum + rl.z);
                ((u16*)out)[(size_t)(r_ + 3) * D_ + c] = f2bf(acc[mi][ni][3] + bsum + rl.w);
            }
        }
    }
}

// ---------- channel-attention scores via MFMA, split-K partials ----------
__global__ __launch_bounds__(256) void scores_partial(const u16* __restrict__ qT,
                                                      const u16* __restrict__ kT,
                                                      float* __restrict__ part) {
    __shared__ u16 qs[64 * 136];
    __shared__ u16 ks[64 * 136];
    const int chunk = blockIdx.x;   // 0..15, 512 l each
    const int bh = blockIdx.y;      // 0..31
    const int b = bh >> 3, h = bh & 7;
    const int tid = threadIdx.x;
    const int wave = tid >> 6, lane = tid & 63;
    const int wr = (wave >> 1) * 32;
    const int wc = (wave & 1) * 32;
    f32x4 acc[2][2];
    #pragma unroll
    for (int mi = 0; mi < 2; ++mi)
        #pragma unroll
        for (int ni = 0; ni < 2; ++ni) acc[mi][ni] = (f32x4){0.f, 0.f, 0.f, 0.f};
    const size_t base = (size_t)(b * D_ + h * 64) * L_;
    const int m = lane & 15, q = lane >> 4;
    for (int iter = 0; iter < 4; ++iter) {
        const int l0 = chunk * 512 + iter * 128;
        __syncthreads();
        for (int i = tid; i < 1024; i += 256) {
            const int lb = i & 15, ch = i >> 4;
            const size_t gidx = base + (size_t)ch * L_ + l0 + lb * 8;
            *(s16x8*)(qs + ch * 136 + lb * 8) = *(const s16x8*)(qT + gidx);
            *(s16x8*)(ks + ch * 136 + lb * 8) = *(const s16x8*)(kT + gidx);
        }
        __syncthreads();
        #pragma unroll
        for (int kst = 0; kst < 4; ++kst) {
            const int kk = kst * 32 + q * 8;
            s16x8 af[2], bfr[2];
            af[0]  = *(const s16x8*)(qs + (wr + m) * 136 + kk);
            af[1]  = *(const s16x8*)(qs + (wr + 16 + m) * 136 + kk);
            bfr[0] = *(const s16x8*)(ks + (wc + m) * 136 + kk);
            bfr[1] = *(const s16x8*)(ks + (wc + 16 + m) * 136 + kk);
            #pragma unroll
            for (int mi = 0; mi < 2; ++mi)
                #pragma unroll
                for (int ni = 0; ni < 2; ++ni)
                    acc[mi][ni] = __builtin_amdgcn_mfma_f32_16x16x32_bf16(af[mi], bfr[ni], acc[mi][ni], 0, 0, 0);
        }
    }
    float* dst = part + (size_t)(bh * 16 + chunk) * 4096;
    const int q4 = (lane >> 4) * 4;
    #pragma unroll
    for (int mi = 0; mi < 2; ++mi) {
        #pragma unroll
        for (int ni = 0; ni < 2; ++ni) {
            const int j = wc + ni * 16 + m;
            #pragma unroll
            for (int rg = 0; rg < 4; ++rg) {
                const int i = wr + mi * 16 + q4 + rg;
                dst[i * 64 + j] = acc[mi][ni][rg];
            }
        }
    }
}

// ---------- sum partials, scale, softmax over last dim ----------
__global__ __launch_bounds__(256) void softmax_kernel(const float* __restrict__ part,
                                                      float* __restrict__ attn) {
    const int tid = threadIdx.x;
    const int wave = tid >> 6, lane = tid & 63;
    const int row = blockIdx.x * 4 + wave;
    const int bh = row >> 6, i = row & 63;
    float s = 0.f;
    #pragma unroll
    for (int c = 0; c < 16; ++c) s += part[((size_t)(bh * 16 + c)) * 4096 + i * 64 + lane];
    s *= 0.04419417382415922f;               // 512^-0.5
    float m = s;
    for (int off = 32; off > 0; off >>= 1) m = fmaxf(m, __shfl_xor(m, off));
    float e = expf(s - m);
    float sum = e;
    for (int off = 32; off > 0; off >>= 1) sum += __shfl_xor(sum, off);
    attn[(size_t)bh * 4096 + i * 64 + lane] = e / sum;
}

// ---------- M[b] = Wout * blockdiag(attn[b]) written in packed B-fragment order ----
__global__ __launch_bounds__(256) void build_M(const float* __restrict__ Wout,
                                               const float* __restrict__ attn,
                                               u16* __restrict__ Mpack) {
    const int idx = blockIdx.x * 256 + threadIdx.x;   // b*512*512 + o*512 + col
    const int col = idx & 511;                        // k (v-channel)
    const int o = (idx >> 9) & 511;                   // out-channel (GEMM col c)
    const int b = idx >> 18;
    const int h = col >> 6, j0 = col & 63;
    const float* wr = Wout + o * 512 + h * 64;
    const float* ar = attn + (size_t)(b * H_ + h) * 4096 + j0;
    float s = 0.f;
    #pragma unroll 8
    for (int i = 0; i < 64; ++i) s += wr[i] * ar[i * 64];
    const int cb = o >> 4, fm = o & 15;
    const int kc = col >> 5, q = (col >> 3) & 3, j = col & 7;
    Mpack[(size_t)b * 262144 + ((size_t)(cb * 16 + kc) * 64 + q * 16 + fm) * 8 + j] = f2bf(s);
}

extern "C" void kernel_launch(void* const* d_in, const int* in_sizes, int n_in,
                              void* d_out, int out_size, void* d_ws, size_t ws_size,
                              hipStream_t stream) {
    const float* x    = (const float*)d_in[0];
    const float* Wq   = (const float*)d_in[1];
    const float* bq   = (const float*)d_in[2];
    const float* Wk   = (const float*)d_in[3];
    const float* bk   = (const float*)d_in[4];
    const float* Wv   = (const float*)d_in[5];
    const float* bv   = (const float*)d_in[6];
    const float* Wo1  = (const float*)d_in[7];
    const float* bo1  = (const float*)d_in[8];
    const float* Wo2  = (const float*)d_in[9];
    const float* bo2  = (const float*)d_in[10];
    const float* rel  = (const float*)d_in[11];
    const float* Wout = (const float*)d_in[12];
    const float* bout = (const float*)d_in[13];

    char* ws = (char*)d_ws;
    const size_t MB = 1024ull * 1024ull;
    const bool big = ws_size >= 165ull * MB;   // bf16-sample path needs ~163.2 MB

    u16* x_bf = (u16*)(ws);                    // 32 MB
    u16* qT   = (u16*)(ws + 32 * MB);          // 32 MB, [b*D+ch][l]
    u16* kT   = (u16*)(ws + 64 * MB);          // 32 MB, [b*D+ch][l]
    u16* v_bf = (u16*)(ws + 96 * MB);          // 32 MB, row-major

    u16*   xs;     // sampled x (bf16 row-major), A-input of gemm_kv
    u16*   Pq; u16* Pk; u16* Pv;
    float* weff; int* p0i; float* w1f;
    float* part; float* attn; u16* Mpack;

    if (big) {
        // xs lives at 128..160 MB while needed (disp 5-6); part/attn/Mpack
        // reuse the same window afterwards (written only at disp 7+, xs dead).
        xs    = (u16*)(ws + 128 * MB);                         // 32 MB
        part  = (float*)(ws + 128 * MB);                       // 8 MB (after xs dead)
        attn  = (float*)((char*)part + 8 * MB);                // 512 KB
        Mpack = (u16*)((char*)attn + 524288);                  // 2 MB
        Pq    = (u16*)(ws + 160 * MB);                         // 512 KB each
        Pk    = Pq + 262144;
        Pv    = Pk + 262144;
        weff  = (float*)(ws + 162 * MB);                       // 642 floats
        p0i   = (int*)(ws + 162 * MB + 65536);                 // 512 KB
        w1f   = (float*)((char*)p0i + 524288);                 // 512 KB
    } else {
        // legacy layout: xs overwrites x_bf (fp32 sampling; x_bf dead after gemm_q)
        xs    = x_bf;
        Pq    = (u16*)(ws + 128 * MB);
        Pk    = Pq + 262144;
        Pv    = Pk + 262144;
        weff  = (float*)(ws + 130 * MB);
        p0i   = (int*)(ws + 130 * MB + 65536);
        w1f   = (float*)((char*)p0i + 524288);
        part  = (float*)((char*)w1f + 524288);
        attn  = (float*)((char*)part + 8 * MB);
        Mpack = (u16*)((char*)attn + 524288);
    }

    // 1. fused prep: cast x -> bf16, pack Wq/Wk/Wv, compose offset convs
    prep_kernel<<<CAST_BLOCKS + PACK_BLOCKS + 3, 256, 0, stream>>>(
        x, x_bf, Wq, Wk, Wv, Pq, Pk, Pv, Wo1, bo1, Wo2, bo2, weff);
    // 2. q = x @ Wq^T  (stored transposed)
    gemm_kernel<0><<<1024, 256, 0, stream>>>(x_bf, Pq, nullptr, bq, nullptr, nullptr, (void*)qT, nullptr);
    // 3. offsets -> sampling positions (reads qT)
    offsets_kernel<<<dim3(128, 16), 256, 0, stream>>>(qT, weff, p0i, w1f);
    // 4. bilinear sample
    if (big) sample_bf16<<<8192, 256, 0, stream>>>(x_bf, p0i, w1f, xs);
    else     sample_f32<<<16384, 256, 0, stream>>>(x, p0i, w1f, xs);
    // 5. k (transposed) + v (row-major + rel) in ONE dispatch
    gemm_kernel<1><<<2048, 256, 0, stream>>>(xs, Pk, Pv, bk, bv, rel, (void*)kT, (void*)v_bf);
    // 6. scores (MFMA) + softmax
    scores_partial<<<dim3(16, 32), 256, 0, stream>>>(qT, kT, part);
    softmax_kernel<<<512, 256, 0, stream>>>(part, attn);
    // 7. fold attn into output projection (packed layout)
    build_M<<<4096, 256, 0, stream>>>(Wout, attn, Mpack);
    // 8. final: out = v @ M[b]^T + bout  (fp32 out)
    gemm_kernel<2><<<1024, 256, 0, stream>>>(v_bf, Mpack, nullptr, bout, nullptr, nullptr, d_out, nullptr);
}